// Round 5
// baseline (418.826 us; speedup 1.0000x reference)
//
#include <hip/hip_runtime.h>

#define S_LEN 1024
#define D_MODELX 1024
#define NHEAD 16
#define DHEAD 64
#define BATCH 8
#define NTOK (BATCH * S_LEN)   // 8192
#define KSCALE 0.18033688011112f   // log2(e)/8, folded into K projection

typedef __bf16 bf16;
typedef __attribute__((ext_vector_type(8))) __bf16 bf16x8;
typedef __attribute__((ext_vector_type(4))) __bf16 bf16x4;
typedef __attribute__((ext_vector_type(4))) float f32x4;

__device__ __forceinline__ void gload_lds16(const void* gsrc, void* ldst) {
  __builtin_amdgcn_global_load_lds(
      (const __attribute__((address_space(1))) void*)gsrc,
      (__attribute__((address_space(3))) void*)ldst,
      16, 0, 0);
}

// ---------------------------------------------------------------- preproc (merged)
#define PRE_ACT_BLKS 8192
#define PRE_W_BLKS 1024
#define PRE_MASK_BLKS 32768
#define PRE_TOTAL (3 * PRE_ACT_BLKS + 4 * PRE_W_BLKS + PRE_MASK_BLKS + 128)
__global__ __launch_bounds__(256) void preproc(
    const float* __restrict__ q, const float* __restrict__ k,
    const float* __restrict__ v, const float* __restrict__ Wq,
    const float* __restrict__ Wk, const float* __restrict__ Wv,
    const float* __restrict__ Wo, const int* __restrict__ mask,
    bf16* __restrict__ Xq, bf16* __restrict__ Xk, bf16* __restrict__ Xv,
    bf16* __restrict__ Wqb, bf16* __restrict__ Wkb, bf16* __restrict__ Wvb,
    bf16* __restrict__ Wob, unsigned long long* __restrict__ mp,
    float* __restrict__ cosT, float* __restrict__ sinT) {
  int blk = blockIdx.x;
  int tid = threadIdx.x;
  if (blk < 3 * PRE_ACT_BLKS + 4 * PRE_W_BLKS) {
    const float* src;
    bf16* dst;
    int l;
    if (blk < PRE_ACT_BLKS) { src = q; dst = Xq; l = blk; }
    else if (blk < 2 * PRE_ACT_BLKS) { src = k; dst = Xk; l = blk - PRE_ACT_BLKS; }
    else if (blk < 3 * PRE_ACT_BLKS) { src = v; dst = Xv; l = blk - 2 * PRE_ACT_BLKS; }
    else if (blk < 3 * PRE_ACT_BLKS + PRE_W_BLKS) { src = Wq; dst = Wqb; l = blk - 3 * PRE_ACT_BLKS; }
    else if (blk < 3 * PRE_ACT_BLKS + 2 * PRE_W_BLKS) { src = Wk; dst = Wkb; l = blk - 3 * PRE_ACT_BLKS - PRE_W_BLKS; }
    else if (blk < 3 * PRE_ACT_BLKS + 3 * PRE_W_BLKS) { src = Wv; dst = Wvb; l = blk - 3 * PRE_ACT_BLKS - 2 * PRE_W_BLKS; }
    else { src = Wo; dst = Wob; l = blk - 3 * PRE_ACT_BLKS - 3 * PRE_W_BLKS; }
    int i = l * 256 + tid;
    float4 val = ((const float4*)src)[i];
    bf16x4 o;
    o[0] = (bf16)val.x; o[1] = (bf16)val.y; o[2] = (bf16)val.z; o[3] = (bf16)val.w;
    ((bf16x4*)dst)[i] = o;
  } else if (blk < 3 * PRE_ACT_BLKS + 4 * PRE_W_BLKS + PRE_MASK_BLKS) {
    int l = blk - (3 * PRE_ACT_BLKS + 4 * PRE_W_BLKS);
    int i = l * 256 + tid;
    unsigned long long bal = __ballot(mask[i] != 0);
    if ((tid & 63) == 0) mp[i >> 6] = bal;
  } else {
    int l = blk - (3 * PRE_ACT_BLKS + 4 * PRE_W_BLKS + PRE_MASK_BLKS);
    int idx = l * 256 + tid;          // 1024*32
    int s = idx >> 5;
    int i = idx & 31;
    float inv = powf(10000.0f, -(float)i / 32.0f);
    float f = (float)s * inv;
    cosT[idx] = cosf(f);
    sinT[idx] = sinf(f);
  }
}

// ---------------------------------------------------------------- fused QKV GEMM
// W3 = [Wq;Wk;Wv] stacked (3072 rows). nblk 0..7 -> Q, 8..15 -> K, 16..23 -> V.
// A (activation) selected per projection. BK=64. 1536 blocks = 6/CU.
// XCD swizzle: xcd = id&7 gets m-panels xcd*8..xcd*8+7, all 24 nblk.
__global__ __launch_bounds__(256) void gemm_qkv(
    const bf16* __restrict__ Xq, const bf16* __restrict__ Xk,
    const bf16* __restrict__ Xv, const bf16* __restrict__ W3,
    const float* __restrict__ bq, const float* __restrict__ bk,
    const float* __restrict__ bv,
    bf16* __restrict__ qws, bf16* __restrict__ kws, bf16* __restrict__ vws,
    const float* __restrict__ cosT, const float* __restrict__ sinT,
    const float* __restrict__ ubias) {
  __shared__ bf16 At[128 * 64];
  __shared__ bf16 Bt[128 * 64];
  const int id = blockIdx.x;            // 0..1535
  const int xcd = id & 7;
  const int idx = id >> 3;              // 0..191
  const int mpan = xcd * 8 + idx / 24;  // 0..63
  const int nblk = idx % 24;
  const int m0 = mpan * 128;
  const int n0 = nblk * 128;
  const int proj = nblk >> 3;           // 0=Q 1=K 2=V
  const bf16* X = proj == 0 ? Xq : proj == 1 ? Xk : Xv;
  const float* bias = proj == 0 ? bq : proj == 1 ? bk : bv;

  const int tid = threadIdx.x;
  const int lane = tid & 63;
  const int wid = tid >> 6;
  const int g = lane >> 4;
  const int li = lane & 15;
  const int wr = (wid >> 1) * 64;
  const int wc = (wid & 1) * 64;

  f32x4 acc[4][4] = {};

  for (int k0 = 0; k0 < D_MODELX; k0 += 64) {
    __syncthreads();
#pragma unroll
    for (int c = 0; c < 4; ++c) {
      int chunk = (c * 4 + wid) * 64 + lane;  // 0..1023 (16B chunks)
      int r = chunk >> 3;
      int seg = chunk & 7;
      gload_lds16(X + (size_t)(m0 + r) * D_MODELX + k0 + seg * 8,
                  &At[((c * 4 + wid) * 64) * 8]);
      gload_lds16(W3 + (size_t)(n0 + r) * D_MODELX + k0 + seg * 8,
                  &Bt[((c * 4 + wid) * 64) * 8]);
    }
    __syncthreads();
#pragma unroll
    for (int kk = 0; kk < 2; ++kk) {
      bf16x8 af[4], bfr[4];
#pragma unroll
      for (int m = 0; m < 4; ++m)
        af[m] = *(const bf16x8*)&At[(wr + m * 16 + li) * 64 + kk * 32 + g * 8];
#pragma unroll
      for (int n = 0; n < 4; ++n)
        bfr[n] = *(const bf16x8*)&Bt[(wc + n * 16 + li) * 64 + kk * 32 + g * 8];
#pragma unroll
      for (int m = 0; m < 4; ++m)
#pragma unroll
        for (int n = 0; n < 4; ++n)
          acc[m][n] = __builtin_amdgcn_mfma_f32_16x16x32_bf16(af[m], bfr[n],
                                                              acc[m][n], 0, 0, 0);
    }
  }

  // epilogue. C/D layout: col = lane&15, row = (lane>>4)*4 + rg
#pragma unroll
  for (int m = 0; m < 4; ++m) {
#pragma unroll
    for (int n = 0; n < 4; ++n) {
      int col = n0 + wc + n * 16 + li;
      int col1k = col & 1023;
      int dh = col1k & 63;
      int h = col1k >> 6;
      if (proj == 2) {
        // V: write transposed (B,H,Dh,S); rg -> consecutive s -> 8B store
        int token0 = m0 + wr + m * 16 + g * 4;
        int s0 = token0 & (S_LEN - 1);
        int b0 = token0 >> 10;
        bf16x4 o;
#pragma unroll
        for (int rg = 0; rg < 4; ++rg) o[rg] = (bf16)(acc[m][n][rg] + bias[col1k]);
        *(bf16x4*)&vws[(((size_t)b0 * NHEAD + h) * DHEAD + dh) * S_LEN + s0] = o;
      } else {
#pragma unroll
        for (int rg = 0; rg < 4; ++rg) {
          int token = m0 + wr + m * 16 + g * 4 + rg;
          float v = acc[m][n][rg] + bias[col1k];
          float p = __shfl_xor(v, 1, 64);  // rope pair partner (adjacent col)
          int s = token & (S_LEN - 1);
          int b = token >> 10;
          int fi = dh >> 1;
          float cv = cosT[s * 32 + fi];
          float sv = sinT[s * 32 + fi];
          float vr = (dh & 1) ? (v * cv + p * sv) : (v * cv - p * sv);
          if (proj == 0) {
            vr += ubias[(h << 6) + dh];
            qws[(((size_t)b * NHEAD + h) * S_LEN + s) * DHEAD + dh] = (bf16)vr;
          } else {
            kws[(((size_t)b * NHEAD + h) * S_LEN + s) * DHEAD + dh] = (bf16)(vr * KSCALE);
          }
        }
      }
    }
  }
}

// ---------------------------------------------------------------- output GEMM
// out = ctx @ Wo^T + bo, fp32 out. BK=64. 512 blocks, XCD swizzle 8x8.
__global__ __launch_bounds__(256) void gemm_out(
    const bf16* __restrict__ X, const bf16* __restrict__ W,
    const float* __restrict__ bias, float* __restrict__ outp) {
  __shared__ bf16 At[128 * 64];
  __shared__ bf16 Bt[128 * 64];
  const int id = blockIdx.x;
  const int swz = (id & 7) * 64 + (id >> 3);
  const int m0 = (swz >> 3) * 128;
  const int n0 = (swz & 7) * 128;
  const int tid = threadIdx.x;
  const int lane = tid & 63;
  const int wid = tid >> 6;
  const int g = lane >> 4;
  const int li = lane & 15;
  const int wr = (wid >> 1) * 64;
  const int wc = (wid & 1) * 64;

  f32x4 acc[4][4] = {};

  for (int k0 = 0; k0 < D_MODELX; k0 += 64) {
    __syncthreads();
#pragma unroll
    for (int c = 0; c < 4; ++c) {
      int chunk = (c * 4 + wid) * 64 + lane;
      int r = chunk >> 3;
      int seg = chunk & 7;
      gload_lds16(X + (size_t)(m0 + r) * D_MODELX + k0 + seg * 8,
                  &At[((c * 4 + wid) * 64) * 8]);
      gload_lds16(W + (size_t)(n0 + r) * D_MODELX + k0 + seg * 8,
                  &Bt[((c * 4 + wid) * 64) * 8]);
    }
    __syncthreads();
#pragma unroll
    for (int kk = 0; kk < 2; ++kk) {
      bf16x8 af[4], bfr[4];
#pragma unroll
      for (int m = 0; m < 4; ++m)
        af[m] = *(const bf16x8*)&At[(wr + m * 16 + li) * 64 + kk * 32 + g * 8];
#pragma unroll
      for (int n = 0; n < 4; ++n)
        bfr[n] = *(const bf16x8*)&Bt[(wc + n * 16 + li) * 64 + kk * 32 + g * 8];
#pragma unroll
      for (int m = 0; m < 4; ++m)
#pragma unroll
        for (int n = 0; n < 4; ++n)
          acc[m][n] = __builtin_amdgcn_mfma_f32_16x16x32_bf16(af[m], bfr[n],
                                                              acc[m][n], 0, 0, 0);
    }
  }

#pragma unroll
  for (int m = 0; m < 4; ++m)
#pragma unroll
    for (int n = 0; n < 4; ++n) {
      int col = n0 + wc + n * 16 + li;
#pragma unroll
      for (int rg = 0; rg < 4; ++rg) {
        int token = m0 + wr + m * 16 + g * 4 + rg;
        outp[(size_t)token * D_MODELX + col] = acc[m][n][rg] + bias[col];
      }
    }
}

// ---------------------------------------------------------------- attention
// Q: (B*H,S,64) bf16 (u_bias folded). K: pre-scaled by log2e/8. V: (B*H,64,S).
// mp: bit-packed mask. ctx: (B,S,1024) bf16. P=exp2(score), sums via ones-MFMA.
__global__ __launch_bounds__(256) void attn_fwd(
    const bf16* __restrict__ Q, const bf16* __restrict__ K,
    const bf16* __restrict__ V, const unsigned long long* __restrict__ mp,
    bf16* __restrict__ ctx) {
  __shared__ bf16 Kl[2][64 * 64];     // [t][d], XOR-swizzled
  __shared__ bf16 Vt[2][64 * 64];     // [d][t], XOR-swizzled
  __shared__ bf16 Pl[4][16 * 64];     // per-wave P [q][t], XOR-swizzled

  const int id = blockIdx.x;          // 2048 = 8 XCD * 256
  const int swz = (id & 7) * 256 + (id >> 3);
  const int bh = swz >> 4;
  const int qblk = swz & 15;
  const int tid = threadIdx.x;
  const int lane = tid & 63;
  const int wid = tid >> 6;
  const int b = bh >> 4;
  const int h = bh & 15;
  const int g = lane >> 4;
  const int li = lane & 15;
  const int q0 = qblk * 64 + wid * 16;

  const bf16* qbase = Q + ((size_t)bh * S_LEN + q0) * DHEAD;
  bf16x8 qf[2];
  qf[0] = *(const bf16x8*)&qbase[(size_t)li * DHEAD + g * 8];
  qf[1] = *(const bf16x8*)&qbase[(size_t)li * DHEAD + 32 + g * 8];

  bf16x8 onesf;
#pragma unroll
  for (int j = 0; j < 8; ++j) onesf[j] = (bf16)1.0f;

  f32x4 ctxacc[4] = {};
  f32x4 sacc = {};

  const bf16* gk = K + (size_t)bh * S_LEN * DHEAD;       // [t][d]
  const bf16* gv = V + (size_t)bh * DHEAD * S_LEN;       // [d][t]
  const unsigned long long* mrowp = mp + ((size_t)b * S_LEN + q0) * 16;

  const int srow = lane >> 3;                // 0..7 within 8-row group
  const int schunk = (lane & 7) ^ srow;      // pre-swizzled global chunk

  auto stage = [&](int bi, int it) {
    int t0 = it * 64;
#pragma unroll
    for (int j = 0; j < 2; ++j) {
      int row = wid * 16 + j * 8 + srow;
      gload_lds16(gk + ((size_t)(t0 + row)) * DHEAD + schunk * 8,
                  &Kl[bi][(wid * 16 + j * 8) * 64]);
      gload_lds16(gv + (size_t)row * S_LEN + t0 + schunk * 8,
                  &Vt[bi][(wid * 16 + j * 8) * 64]);
    }
  };

  stage(0, 0);
  int buf = 0;

  for (int it = 0; it < S_LEN / 64; ++it) {
    asm volatile("s_waitcnt vmcnt(0)" ::: "memory");
    __builtin_amdgcn_s_barrier();
    if (it + 1 < S_LEN / 64) stage(buf ^ 1, it + 1);

    // packed mask words for this tile (one 64-bit word per q-row)
    unsigned long long mw[4];
#pragma unroll
    for (int rg = 0; rg < 4; ++rg)
      mw[rg] = mrowp[(size_t)(g * 4 + rg) * 16 + it];

    // QK^T: sc[tt][rg] = log2-domain score[q = g*4+rg][t-local = tt*16 + li]
    f32x4 sc[4];
    __builtin_amdgcn_s_setprio(1);
#pragma unroll
    for (int tt = 0; tt < 4; ++tt) {
      int row = tt * 16 + li;
      int sz = li & 7;
      bf16x8 kf0 = *(const bf16x8*)&Kl[buf][row * 64 + ((g ^ sz) << 3)];
      bf16x8 kf1 = *(const bf16x8*)&Kl[buf][row * 64 + (((g + 4) ^ sz) << 3)];
      f32x4 a = {};
      a = __builtin_amdgcn_mfma_f32_16x16x32_bf16(qf[0], kf0, a, 0, 0, 0);
      a = __builtin_amdgcn_mfma_f32_16x16x32_bf16(qf[1], kf1, a, 0, 0, 0);
      sc[tt] = a;
    }
    __builtin_amdgcn_s_setprio(0);

    // P = exp2(score), masked -> 0; write to per-wave LDS (swizzled)
#pragma unroll
    for (int rg = 0; rg < 4; ++rg) {
      unsigned long long msh = mw[rg] >> li;
      unsigned int mlo = (unsigned int)msh;
      unsigned int mhi = (unsigned int)(msh >> 32);
      int qq = g * 4 + rg;
#pragma unroll
      for (int tt = 0; tt < 4; ++tt) {
        unsigned int half = (tt & 2) ? mhi : mlo;
        unsigned int bit = (half >> ((tt & 1) << 4)) & 1u;
        float p = exp2f(sc[tt][rg]);
        p = bit ? 0.0f : p;
        int t = tt * 16 + li;
        Pl[wid][qq * 64 + (t ^ ((qq & 7) << 3))] = (bf16)p;
      }
    }

    // PV + row-sum: ctx[q][d] += P[q][t]*Vt[d][t];  sacc[q] += P[q][t]*1
    __builtin_amdgcn_s_setprio(1);
#pragma unroll
    for (int sub = 0; sub < 2; ++sub) {
      bf16x8 pf = *(const bf16x8*)&Pl[wid][li * 64 + (((sub * 4 + g) ^ (li & 7)) << 3)];
      sacc = __builtin_amdgcn_mfma_f32_16x16x32_bf16(pf, onesf, sacc, 0, 0, 0);
#pragma unroll
      for (int dd = 0; dd < 4; ++dd) {
        int row = dd * 16 + li;
        bf16x8 vf = *(const bf16x8*)&Vt[buf][row * 64 + (((sub * 4 + g) ^ (row & 7)) << 3)];
        ctxacc[dd] = __builtin_amdgcn_mfma_f32_16x16x32_bf16(pf, vf, ctxacc[dd], 0, 0, 0);
      }
    }
    __builtin_amdgcn_s_setprio(0);
    buf ^= 1;
  }

  // normalize + store ctx (B,S,D) bf16
  float inv[4];
#pragma unroll
  for (int rg = 0; rg < 4; ++rg) inv[rg] = 1.0f / sacc[rg];
#pragma unroll
  for (int dd = 0; dd < 4; ++dd)
#pragma unroll
    for (int rg = 0; rg < 4; ++rg) {
      float vout = ctxacc[dd][rg] * inv[rg];
      int s = q0 + g * 4 + rg;
      int d = h * 64 + dd * 16 + li;
      ctx[((size_t)b * S_LEN + s) * D_MODELX + d] = (bf16)vout;
    }
}

// ---------------------------------------------------------------- launcher
extern "C" void kernel_launch(void* const* d_in, const int* in_sizes, int n_in,
                              void* d_out, int out_size, void* d_ws, size_t ws_size,
                              hipStream_t stream) {
  const float* query = (const float*)d_in[0];
  const float* key   = (const float*)d_in[1];
  const float* value = (const float*)d_in[2];
  const int*   mask  = (const int*)d_in[3];
  const float* Wq = (const float*)d_in[4];
  const float* bq = (const float*)d_in[5];
  const float* Wk = (const float*)d_in[6];
  const float* bk = (const float*)d_in[7];
  const float* Wv = (const float*)d_in[8];
  const float* bv = (const float*)d_in[9];
  const float* ub = (const float*)d_in[10];
  const float* Wo = (const float*)d_in[11];
  const float* bo = (const float*)d_in[12];
  float* out = (float*)d_out;

  char* wsb = (char*)d_ws;
  size_t off = 0;
  auto give = [&](size_t bytes) -> char* {
    char* p = wsb + off;
    off += (bytes + 255) & ~(size_t)255;
    return p;
  };
  const size_t ACT = (size_t)NTOK * D_MODELX * 2;   // 16.78 MB
  const size_t WB  = (size_t)D_MODELX * D_MODELX * 2;
  bf16* Xq   = (bf16*)give(ACT);
  bf16* Xk   = (bf16*)give(ACT);
  bf16* Xv   = (bf16*)give(ACT);
  bf16* Wqb  = (bf16*)give(WB);    // Wqb/Wkb/Wvb contiguous -> W3 [3072][1024]
  bf16* Wkb  = (bf16*)give(WB);
  bf16* Wvb  = (bf16*)give(WB);
  bf16* Wob  = (bf16*)give(WB);
  bf16* qws  = (bf16*)give(ACT);   // (B,H,S,Dh)
  bf16* kws  = (bf16*)give(ACT);   // (B,H,S,Dh), pre-scaled
  bf16* vws  = (bf16*)give(ACT);   // (B,H,Dh,S)  TRANSPOSED
  unsigned long long* mp = (unsigned long long*)give((size_t)BATCH * S_LEN * 16 * 8);
  float* cosT = (float*)give((size_t)S_LEN * 32 * 4);
  float* sinT = (float*)give((size_t)S_LEN * 32 * 4);
  bf16* ctxw = Xq;                 // Xq dead after QKV GEMM; reuse (B,S,D)

  preproc<<<PRE_TOTAL, 256, 0, stream>>>(query, key, value, Wq, Wk, Wv, Wo, mask,
                                         Xq, Xk, Xv, Wqb, Wkb, Wvb, Wob, mp,
                                         cosT, sinT);

  gemm_qkv<<<1536, 256, 0, stream>>>(Xq, Xk, Xv, Wqb, bq, bk, bv,
                                     qws, kws, vws, cosT, sinT, ub);

  attn_fwd<<<2048, 256, 0, stream>>>(qws, kws, vws, mp, ctxw);

  gemm_out<<<512, 256, 0, stream>>>(ctxw, Wob, bo, out);
}

// Round 6
// 398.889 us; speedup vs baseline: 1.0500x; 1.0500x over previous
//
#include <hip/hip_runtime.h>

#define S_LEN 1024
#define D_MODELX 1024
#define NHEAD 16
#define DHEAD 64
#define BATCH 8
#define NTOK (BATCH * S_LEN)   // 8192
#define KSCALE 0.18033688011112f   // log2(e)/8, folded into K projection

typedef __bf16 bf16;
typedef __attribute__((ext_vector_type(8))) __bf16 bf16x8;
typedef __attribute__((ext_vector_type(4))) __bf16 bf16x4;
typedef __attribute__((ext_vector_type(4))) float f32x4;

__device__ __forceinline__ void gload_lds16(const void* gsrc, void* ldst) {
  __builtin_amdgcn_global_load_lds(
      (const __attribute__((address_space(1))) void*)gsrc,
      (__attribute__((address_space(3))) void*)ldst,
      16, 0, 0);
}

// ---------------------------------------------------------------- preproc (merged)
#define PRE_ACT_BLKS 8192
#define PRE_W_BLKS 1024
#define PRE_MASK_BLKS 32768
#define PRE_TOTAL (3 * PRE_ACT_BLKS + 4 * PRE_W_BLKS + PRE_MASK_BLKS + 128)
__global__ __launch_bounds__(256) void preproc(
    const float* __restrict__ q, const float* __restrict__ k,
    const float* __restrict__ v, const float* __restrict__ Wq,
    const float* __restrict__ Wk, const float* __restrict__ Wv,
    const float* __restrict__ Wo, const int* __restrict__ mask,
    bf16* __restrict__ Xq, bf16* __restrict__ Xk, bf16* __restrict__ Xv,
    bf16* __restrict__ Wqb, bf16* __restrict__ Wkb, bf16* __restrict__ Wvb,
    bf16* __restrict__ Wob, unsigned long long* __restrict__ mp,
    float* __restrict__ cosT, float* __restrict__ sinT) {
  int blk = blockIdx.x;
  int tid = threadIdx.x;
  if (blk < 3 * PRE_ACT_BLKS + 4 * PRE_W_BLKS) {
    const float* src;
    bf16* dst;
    int l;
    if (blk < PRE_ACT_BLKS) { src = q; dst = Xq; l = blk; }
    else if (blk < 2 * PRE_ACT_BLKS) { src = k; dst = Xk; l = blk - PRE_ACT_BLKS; }
    else if (blk < 3 * PRE_ACT_BLKS) { src = v; dst = Xv; l = blk - 2 * PRE_ACT_BLKS; }
    else if (blk < 3 * PRE_ACT_BLKS + PRE_W_BLKS) { src = Wq; dst = Wqb; l = blk - 3 * PRE_ACT_BLKS; }
    else if (blk < 3 * PRE_ACT_BLKS + 2 * PRE_W_BLKS) { src = Wk; dst = Wkb; l = blk - 3 * PRE_ACT_BLKS - PRE_W_BLKS; }
    else if (blk < 3 * PRE_ACT_BLKS + 3 * PRE_W_BLKS) { src = Wv; dst = Wvb; l = blk - 3 * PRE_ACT_BLKS - 2 * PRE_W_BLKS; }
    else { src = Wo; dst = Wob; l = blk - 3 * PRE_ACT_BLKS - 3 * PRE_W_BLKS; }
    int i = l * 256 + tid;
    float4 val = ((const float4*)src)[i];
    bf16x4 o;
    o[0] = (bf16)val.x; o[1] = (bf16)val.y; o[2] = (bf16)val.z; o[3] = (bf16)val.w;
    ((bf16x4*)dst)[i] = o;
  } else if (blk < 3 * PRE_ACT_BLKS + 4 * PRE_W_BLKS + PRE_MASK_BLKS) {
    int l = blk - (3 * PRE_ACT_BLKS + 4 * PRE_W_BLKS);
    int i = l * 256 + tid;
    unsigned long long bal = __ballot(mask[i] != 0);
    if ((tid & 63) == 0) mp[i >> 6] = bal;
  } else {
    int l = blk - (3 * PRE_ACT_BLKS + 4 * PRE_W_BLKS + PRE_MASK_BLKS);
    int idx = l * 256 + tid;          // 1024*32
    int s = idx >> 5;
    int i = idx & 31;
    float inv = powf(10000.0f, -(float)i / 32.0f);
    float f = (float)s * inv;
    cosT[idx] = cosf(f);
    sinT[idx] = sinf(f);
  }
}

// ---------------------------------------------------------------- fused QKV GEMM
// W3 = [Wq;Wk;Wv] stacked (3072 rows). nblk 0..7 -> Q, 8..15 -> K, 16..23 -> V.
// BK=64; LDS rows are 128B so we XOR-swizzle 16B chunks within each row:
// LDS slot (r, seg) holds global chunk seg^(r&7); reads XOR the same way
// (identical pattern to attn_fwd, measured 0 bank conflicts).
__global__ __launch_bounds__(256) void gemm_qkv(
    const bf16* __restrict__ Xq, const bf16* __restrict__ Xk,
    const bf16* __restrict__ Xv, const bf16* __restrict__ W3,
    const float* __restrict__ bq, const float* __restrict__ bk,
    const float* __restrict__ bv,
    bf16* __restrict__ qws, bf16* __restrict__ kws, bf16* __restrict__ vws,
    const float* __restrict__ cosT, const float* __restrict__ sinT,
    const float* __restrict__ ubias) {
  __shared__ bf16 At[128 * 64];
  __shared__ bf16 Bt[128 * 64];
  const int id = blockIdx.x;            // 0..1535
  const int xcd = id & 7;
  const int idx = id >> 3;              // 0..191
  const int mpan = xcd * 8 + idx / 24;  // 0..63
  const int nblk = idx % 24;
  const int m0 = mpan * 128;
  const int n0 = nblk * 128;
  const int proj = nblk >> 3;           // 0=Q 1=K 2=V
  const bf16* X = proj == 0 ? Xq : proj == 1 ? Xk : Xv;
  const float* bias = proj == 0 ? bq : proj == 1 ? bk : bv;

  const int tid = threadIdx.x;
  const int lane = tid & 63;
  const int wid = tid >> 6;
  const int g = lane >> 4;
  const int li = lane & 15;
  const int wr = (wid >> 1) * 64;
  const int wc = (wid & 1) * 64;

  f32x4 acc[4][4] = {};

  for (int k0 = 0; k0 < D_MODELX; k0 += 64) {
    __syncthreads();
#pragma unroll
    for (int c = 0; c < 4; ++c) {
      int chunk = (c * 4 + wid) * 64 + lane;  // linear LDS 16B-slot index
      int r = chunk >> 3;
      int seg = (chunk & 7) ^ (r & 7);        // pre-swizzled global chunk
      gload_lds16(X + (size_t)(m0 + r) * D_MODELX + k0 + seg * 8,
                  &At[((c * 4 + wid) * 64) * 8]);
      gload_lds16(W3 + (size_t)(n0 + r) * D_MODELX + k0 + seg * 8,
                  &Bt[((c * 4 + wid) * 64) * 8]);
    }
    __syncthreads();
#pragma unroll
    for (int kk = 0; kk < 2; ++kk) {
      bf16x8 af[4], bfr[4];
#pragma unroll
      for (int m = 0; m < 4; ++m) {
        int row = wr + m * 16 + li;
        af[m] = *(const bf16x8*)&At[row * 64 + (((kk * 4 + g) ^ (row & 7)) << 3)];
      }
#pragma unroll
      for (int n = 0; n < 4; ++n) {
        int row = wc + n * 16 + li;
        bfr[n] = *(const bf16x8*)&Bt[row * 64 + (((kk * 4 + g) ^ (row & 7)) << 3)];
      }
#pragma unroll
      for (int m = 0; m < 4; ++m)
#pragma unroll
        for (int n = 0; n < 4; ++n)
          acc[m][n] = __builtin_amdgcn_mfma_f32_16x16x32_bf16(af[m], bfr[n],
                                                              acc[m][n], 0, 0, 0);
    }
  }

  // epilogue. C/D layout: col = lane&15, row = (lane>>4)*4 + rg
#pragma unroll
  for (int m = 0; m < 4; ++m) {
#pragma unroll
    for (int n = 0; n < 4; ++n) {
      int col = n0 + wc + n * 16 + li;
      int col1k = col & 1023;
      int dh = col1k & 63;
      int h = col1k >> 6;
      if (proj == 2) {
        // V: write transposed (B,H,Dh,S); rg -> consecutive s -> 8B store
        int token0 = m0 + wr + m * 16 + g * 4;
        int s0 = token0 & (S_LEN - 1);
        int b0 = token0 >> 10;
        bf16x4 o;
#pragma unroll
        for (int rg = 0; rg < 4; ++rg) o[rg] = (bf16)(acc[m][n][rg] + bias[col1k]);
        *(bf16x4*)&vws[(((size_t)b0 * NHEAD + h) * DHEAD + dh) * S_LEN + s0] = o;
      } else {
#pragma unroll
        for (int rg = 0; rg < 4; ++rg) {
          int token = m0 + wr + m * 16 + g * 4 + rg;
          float v = acc[m][n][rg] + bias[col1k];
          float p = __shfl_xor(v, 1, 64);  // rope pair partner (adjacent col)
          int s = token & (S_LEN - 1);
          int b = token >> 10;
          int fi = dh >> 1;
          float cv = cosT[s * 32 + fi];
          float sv = sinT[s * 32 + fi];
          float vr = (dh & 1) ? (v * cv + p * sv) : (v * cv - p * sv);
          if (proj == 0) {
            vr += ubias[(h << 6) + dh];
            qws[(((size_t)b * NHEAD + h) * S_LEN + s) * DHEAD + dh] = (bf16)vr;
          } else {
            kws[(((size_t)b * NHEAD + h) * S_LEN + s) * DHEAD + dh] = (bf16)(vr * KSCALE);
          }
        }
      }
    }
  }
}

// ---------------------------------------------------------------- output GEMM
// out = ctx @ Wo^T + bo, fp32 out. BK=64 + same XOR swizzle. 512 blocks.
__global__ __launch_bounds__(256) void gemm_out(
    const bf16* __restrict__ X, const bf16* __restrict__ W,
    const float* __restrict__ bias, float* __restrict__ outp) {
  __shared__ bf16 At[128 * 64];
  __shared__ bf16 Bt[128 * 64];
  const int id = blockIdx.x;
  const int swz = (id & 7) * 64 + (id >> 3);
  const int m0 = (swz >> 3) * 128;
  const int n0 = (swz & 7) * 128;
  const int tid = threadIdx.x;
  const int lane = tid & 63;
  const int wid = tid >> 6;
  const int g = lane >> 4;
  const int li = lane & 15;
  const int wr = (wid >> 1) * 64;
  const int wc = (wid & 1) * 64;

  f32x4 acc[4][4] = {};

  for (int k0 = 0; k0 < D_MODELX; k0 += 64) {
    __syncthreads();
#pragma unroll
    for (int c = 0; c < 4; ++c) {
      int chunk = (c * 4 + wid) * 64 + lane;
      int r = chunk >> 3;
      int seg = (chunk & 7) ^ (r & 7);
      gload_lds16(X + (size_t)(m0 + r) * D_MODELX + k0 + seg * 8,
                  &At[((c * 4 + wid) * 64) * 8]);
      gload_lds16(W + (size_t)(n0 + r) * D_MODELX + k0 + seg * 8,
                  &Bt[((c * 4 + wid) * 64) * 8]);
    }
    __syncthreads();
#pragma unroll
    for (int kk = 0; kk < 2; ++kk) {
      bf16x8 af[4], bfr[4];
#pragma unroll
      for (int m = 0; m < 4; ++m) {
        int row = wr + m * 16 + li;
        af[m] = *(const bf16x8*)&At[row * 64 + (((kk * 4 + g) ^ (row & 7)) << 3)];
      }
#pragma unroll
      for (int n = 0; n < 4; ++n) {
        int row = wc + n * 16 + li;
        bfr[n] = *(const bf16x8*)&Bt[row * 64 + (((kk * 4 + g) ^ (row & 7)) << 3)];
      }
#pragma unroll
      for (int m = 0; m < 4; ++m)
#pragma unroll
        for (int n = 0; n < 4; ++n)
          acc[m][n] = __builtin_amdgcn_mfma_f32_16x16x32_bf16(af[m], bfr[n],
                                                              acc[m][n], 0, 0, 0);
    }
  }

#pragma unroll
  for (int m = 0; m < 4; ++m)
#pragma unroll
    for (int n = 0; n < 4; ++n) {
      int col = n0 + wc + n * 16 + li;
#pragma unroll
      for (int rg = 0; rg < 4; ++rg) {
        int token = m0 + wr + m * 16 + g * 4 + rg;
        outp[(size_t)token * D_MODELX + col] = acc[m][n][rg] + bias[col];
      }
    }
}

// ---------------------------------------------------------------- attention
// Q: (B*H,S,64) bf16 (u_bias folded). K: pre-scaled by log2e/8. V: (B*H,64,S).
// mp: bit-packed mask. ctx: (B,S,1024) bf16. P=exp2(score), sums via ones-MFMA.
__global__ __launch_bounds__(256) void attn_fwd(
    const bf16* __restrict__ Q, const bf16* __restrict__ K,
    const bf16* __restrict__ V, const unsigned long long* __restrict__ mp,
    bf16* __restrict__ ctx) {
  __shared__ bf16 Kl[2][64 * 64];     // [t][d], XOR-swizzled
  __shared__ bf16 Vt[2][64 * 64];     // [d][t], XOR-swizzled
  __shared__ bf16 Pl[4][16 * 64];     // per-wave P [q][t], XOR-swizzled

  const int id = blockIdx.x;          // 2048 = 8 XCD * 256
  const int swz = (id & 7) * 256 + (id >> 3);
  const int bh = swz >> 4;
  const int qblk = swz & 15;
  const int tid = threadIdx.x;
  const int lane = tid & 63;
  const int wid = tid >> 6;
  const int b = bh >> 4;
  const int h = bh & 15;
  const int g = lane >> 4;
  const int li = lane & 15;
  const int q0 = qblk * 64 + wid * 16;

  const bf16* qbase = Q + ((size_t)bh * S_LEN + q0) * DHEAD;
  bf16x8 qf[2];
  qf[0] = *(const bf16x8*)&qbase[(size_t)li * DHEAD + g * 8];
  qf[1] = *(const bf16x8*)&qbase[(size_t)li * DHEAD + 32 + g * 8];

  bf16x8 onesf;
#pragma unroll
  for (int j = 0; j < 8; ++j) onesf[j] = (bf16)1.0f;

  f32x4 ctxacc[4] = {};
  f32x4 sacc = {};

  const bf16* gk = K + (size_t)bh * S_LEN * DHEAD;       // [t][d]
  const bf16* gv = V + (size_t)bh * DHEAD * S_LEN;       // [d][t]
  const unsigned long long* mrowp = mp + ((size_t)b * S_LEN + q0) * 16;

  const int srow = lane >> 3;                // 0..7 within 8-row group
  const int schunk = (lane & 7) ^ srow;      // pre-swizzled global chunk

  auto stage = [&](int bi, int it) {
    int t0 = it * 64;
#pragma unroll
    for (int j = 0; j < 2; ++j) {
      int row = wid * 16 + j * 8 + srow;
      gload_lds16(gk + ((size_t)(t0 + row)) * DHEAD + schunk * 8,
                  &Kl[bi][(wid * 16 + j * 8) * 64]);
      gload_lds16(gv + (size_t)row * S_LEN + t0 + schunk * 8,
                  &Vt[bi][(wid * 16 + j * 8) * 64]);
    }
  };

  stage(0, 0);
  int buf = 0;

  for (int it = 0; it < S_LEN / 64; ++it) {
    asm volatile("s_waitcnt vmcnt(0)" ::: "memory");
    __builtin_amdgcn_s_barrier();
    if (it + 1 < S_LEN / 64) stage(buf ^ 1, it + 1);

    // packed mask words for this tile (one 64-bit word per q-row)
    unsigned long long mw[4];
#pragma unroll
    for (int rg = 0; rg < 4; ++rg)
      mw[rg] = mrowp[(size_t)(g * 4 + rg) * 16 + it];

    // QK^T: sc[tt][rg] = log2-domain score[q = g*4+rg][t-local = tt*16 + li]
    f32x4 sc[4];
    __builtin_amdgcn_s_setprio(1);
#pragma unroll
    for (int tt = 0; tt < 4; ++tt) {
      int row = tt * 16 + li;
      int sz = li & 7;
      bf16x8 kf0 = *(const bf16x8*)&Kl[buf][row * 64 + ((g ^ sz) << 3)];
      bf16x8 kf1 = *(const bf16x8*)&Kl[buf][row * 64 + (((g + 4) ^ sz) << 3)];
      f32x4 a = {};
      a = __builtin_amdgcn_mfma_f32_16x16x32_bf16(qf[0], kf0, a, 0, 0, 0);
      a = __builtin_amdgcn_mfma_f32_16x16x32_bf16(qf[1], kf1, a, 0, 0, 0);
      sc[tt] = a;
    }
    __builtin_amdgcn_s_setprio(0);

    // P = exp2(score), masked -> 0; write to per-wave LDS (swizzled)
#pragma unroll
    for (int rg = 0; rg < 4; ++rg) {
      unsigned long long msh = mw[rg] >> li;
      unsigned int mlo = (unsigned int)msh;
      unsigned int mhi = (unsigned int)(msh >> 32);
      int qq = g * 4 + rg;
#pragma unroll
      for (int tt = 0; tt < 4; ++tt) {
        unsigned int half = (tt & 2) ? mhi : mlo;
        unsigned int bit = (half >> ((tt & 1) << 4)) & 1u;
        float p = exp2f(sc[tt][rg]);
        p = bit ? 0.0f : p;
        int t = tt * 16 + li;
        Pl[wid][qq * 64 + (t ^ ((qq & 7) << 3))] = (bf16)p;
      }
    }

    // PV + row-sum: ctx[q][d] += P[q][t]*Vt[d][t];  sacc[q] += P[q][t]*1
    __builtin_amdgcn_s_setprio(1);
#pragma unroll
    for (int sub = 0; sub < 2; ++sub) {
      bf16x8 pf = *(const bf16x8*)&Pl[wid][li * 64 + (((sub * 4 + g) ^ (li & 7)) << 3)];
      sacc = __builtin_amdgcn_mfma_f32_16x16x32_bf16(pf, onesf, sacc, 0, 0, 0);
#pragma unroll
      for (int dd = 0; dd < 4; ++dd) {
        int row = dd * 16 + li;
        bf16x8 vf = *(const bf16x8*)&Vt[buf][row * 64 + (((sub * 4 + g) ^ (row & 7)) << 3)];
        ctxacc[dd] = __builtin_amdgcn_mfma_f32_16x16x32_bf16(pf, vf, ctxacc[dd], 0, 0, 0);
      }
    }
    __builtin_amdgcn_s_setprio(0);
    buf ^= 1;
  }

  // normalize + store ctx (B,S,D) bf16
  float inv[4];
#pragma unroll
  for (int rg = 0; rg < 4; ++rg) inv[rg] = 1.0f / sacc[rg];
#pragma unroll
  for (int dd = 0; dd < 4; ++dd)
#pragma unroll
    for (int rg = 0; rg < 4; ++rg) {
      float vout = ctxacc[dd][rg] * inv[rg];
      int s = q0 + g * 4 + rg;
      int d = h * 64 + dd * 16 + li;
      ctx[((size_t)b * S_LEN + s) * D_MODELX + d] = (bf16)vout;
    }
}

// ---------------------------------------------------------------- launcher
extern "C" void kernel_launch(void* const* d_in, const int* in_sizes, int n_in,
                              void* d_out, int out_size, void* d_ws, size_t ws_size,
                              hipStream_t stream) {
  const float* query = (const float*)d_in[0];
  const float* key   = (const float*)d_in[1];
  const float* value = (const float*)d_in[2];
  const int*   mask  = (const int*)d_in[3];
  const float* Wq = (const float*)d_in[4];
  const float* bq = (const float*)d_in[5];
  const float* Wk = (const float*)d_in[6];
  const float* bk = (const float*)d_in[7];
  const float* Wv = (const float*)d_in[8];
  const float* bv = (const float*)d_in[9];
  const float* ub = (const float*)d_in[10];
  const float* Wo = (const float*)d_in[11];
  const float* bo = (const float*)d_in[12];
  float* out = (float*)d_out;

  char* wsb = (char*)d_ws;
  size_t off = 0;
  auto give = [&](size_t bytes) -> char* {
    char* p = wsb + off;
    off += (bytes + 255) & ~(size_t)255;
    return p;
  };
  const size_t ACT = (size_t)NTOK * D_MODELX * 2;   // 16.78 MB
  const size_t WB  = (size_t)D_MODELX * D_MODELX * 2;
  bf16* Xq   = (bf16*)give(ACT);
  bf16* Xk   = (bf16*)give(ACT);
  bf16* Xv   = (bf16*)give(ACT);
  bf16* Wqb  = (bf16*)give(WB);    // Wqb/Wkb/Wvb contiguous -> W3 [3072][1024]
  bf16* Wkb  = (bf16*)give(WB);
  bf16* Wvb  = (bf16*)give(WB);
  bf16* Wob  = (bf16*)give(WB);
  bf16* qws  = (bf16*)give(ACT);   // (B,H,S,Dh)
  bf16* kws  = (bf16*)give(ACT);   // (B,H,S,Dh), pre-scaled
  bf16* vws  = (bf16*)give(ACT);   // (B,H,Dh,S)  TRANSPOSED
  unsigned long long* mp = (unsigned long long*)give((size_t)BATCH * S_LEN * 16 * 8);
  float* cosT = (float*)give((size_t)S_LEN * 32 * 4);
  float* sinT = (float*)give((size_t)S_LEN * 32 * 4);
  bf16* ctxw = Xq;                 // Xq dead after QKV GEMM; reuse (B,S,D)

  preproc<<<PRE_TOTAL, 256, 0, stream>>>(query, key, value, Wq, Wk, Wv, Wo, mask,
                                         Xq, Xk, Xv, Wqb, Wkb, Wvb, Wob, mp,
                                         cosT, sinT);

  gemm_qkv<<<1536, 256, 0, stream>>>(Xq, Xk, Xv, Wqb, bq, bk, bv,
                                     qws, kws, vws, cosT, sinT, ub);

  attn_fwd<<<2048, 256, 0, stream>>>(qws, kws, vws, mp, ctxw);

  gemm_out<<<512, 256, 0, stream>>>(ctxw, Wob, bo, out);
}

// Round 8
// 382.184 us; speedup vs baseline: 1.0959x; 1.0437x over previous
//
#include <hip/hip_runtime.h>

#define S_LEN 1024
#define D_MODELX 1024
#define NHEAD 16
#define DHEAD 64
#define BATCH 8
#define NTOK (BATCH * S_LEN)   // 8192
#define KSCALE 0.18033688011112f   // log2(e)/8, folded into K projection

typedef __bf16 bf16;
typedef __attribute__((ext_vector_type(8))) __bf16 bf16x8;
typedef __attribute__((ext_vector_type(4))) __bf16 bf16x4;
typedef __attribute__((ext_vector_type(4))) float f32x4;

__device__ __forceinline__ void gload_lds16(const void* gsrc, void* ldst) {
  __builtin_amdgcn_global_load_lds(
      (const __attribute__((address_space(1))) void*)gsrc,
      (__attribute__((address_space(3))) void*)ldst,
      16, 0, 0);
}

// ---------------------------------------------------------------- preproc (merged)
#define PRE_ACT_BLKS 8192
#define PRE_W_BLKS 1024
#define PRE_MASK_BLKS 32768
#define PRE_TOTAL (3 * PRE_ACT_BLKS + 4 * PRE_W_BLKS + PRE_MASK_BLKS + 128)
__global__ __launch_bounds__(256) void preproc(
    const float* __restrict__ q, const float* __restrict__ k,
    const float* __restrict__ v, const float* __restrict__ Wq,
    const float* __restrict__ Wk, const float* __restrict__ Wv,
    const float* __restrict__ Wo, const int* __restrict__ mask,
    bf16* __restrict__ Xq, bf16* __restrict__ Xk, bf16* __restrict__ Xv,
    bf16* __restrict__ Wqb, bf16* __restrict__ Wkb, bf16* __restrict__ Wvb,
    bf16* __restrict__ Wob, unsigned long long* __restrict__ mp,
    float* __restrict__ cosT, float* __restrict__ sinT) {
  int blk = blockIdx.x;
  int tid = threadIdx.x;
  if (blk < 3 * PRE_ACT_BLKS + 4 * PRE_W_BLKS) {
    const float* src;
    bf16* dst;
    int l;
    if (blk < PRE_ACT_BLKS) { src = q; dst = Xq; l = blk; }
    else if (blk < 2 * PRE_ACT_BLKS) { src = k; dst = Xk; l = blk - PRE_ACT_BLKS; }
    else if (blk < 3 * PRE_ACT_BLKS) { src = v; dst = Xv; l = blk - 2 * PRE_ACT_BLKS; }
    else if (blk < 3 * PRE_ACT_BLKS + PRE_W_BLKS) { src = Wq; dst = Wqb; l = blk - 3 * PRE_ACT_BLKS; }
    else if (blk < 3 * PRE_ACT_BLKS + 2 * PRE_W_BLKS) { src = Wk; dst = Wkb; l = blk - 3 * PRE_ACT_BLKS - PRE_W_BLKS; }
    else if (blk < 3 * PRE_ACT_BLKS + 3 * PRE_W_BLKS) { src = Wv; dst = Wvb; l = blk - 3 * PRE_ACT_BLKS - 2 * PRE_W_BLKS; }
    else { src = Wo; dst = Wob; l = blk - 3 * PRE_ACT_BLKS - 3 * PRE_W_BLKS; }
    int i = l * 256 + tid;
    float4 val = ((const float4*)src)[i];
    bf16x4 o;
    o[0] = (bf16)val.x; o[1] = (bf16)val.y; o[2] = (bf16)val.z; o[3] = (bf16)val.w;
    ((bf16x4*)dst)[i] = o;
  } else if (blk < 3 * PRE_ACT_BLKS + 4 * PRE_W_BLKS + PRE_MASK_BLKS) {
    int l = blk - (3 * PRE_ACT_BLKS + 4 * PRE_W_BLKS);
    int i = l * 256 + tid;
    unsigned long long bal = __ballot(mask[i] != 0);
    if ((tid & 63) == 0) mp[i >> 6] = bal;
  } else {
    int l = blk - (3 * PRE_ACT_BLKS + 4 * PRE_W_BLKS + PRE_MASK_BLKS);
    int idx = l * 256 + tid;          // 1024*32
    int s = idx >> 5;
    int i = idx & 31;
    float inv = powf(10000.0f, -(float)i / 32.0f);
    float f = (float)s * inv;
    cosT[idx] = cosf(f);
    sinT[idx] = sinf(f);
  }
}

// ---------------------------------------------------------------- fused QKV GEMM
// W3 = [Wq;Wk;Wv] stacked (3072 rows). BK=64, double-buffered LDS (64 KB),
// counted vmcnt(8): next tile's 8 loads stay in flight across the barrier (T4).
// XOR chunk swizzle (LDS slot (r,seg) holds global chunk seg^(r&7)).
// Block map: xcd = id&7; within XCD, nblk-major so the 8 blocks sharing a
// W-panel run concurrently (L2-resident W).
__global__ __launch_bounds__(256) void gemm_qkv(
    const bf16* __restrict__ Xq, const bf16* __restrict__ Xk,
    const bf16* __restrict__ Xv, const bf16* __restrict__ W3,
    const float* __restrict__ bq, const float* __restrict__ bk,
    const float* __restrict__ bv,
    bf16* __restrict__ qws, bf16* __restrict__ kws, bf16* __restrict__ vws,
    const float* __restrict__ cosT, const float* __restrict__ sinT,
    const float* __restrict__ ubias) {
  __shared__ bf16 At[2][128 * 64];
  __shared__ bf16 Bt[2][128 * 64];
  const int id = blockIdx.x;            // 0..1535
  const int xcd = id & 7;
  const int idx = id >> 3;              // 0..191
  const int nblk = idx >> 3;            // 0..23  (W-panel major)
  const int mpan = xcd * 8 + (idx & 7); // 0..63
  const int m0 = mpan * 128;
  const int n0 = nblk * 128;
  const int proj = nblk >> 3;           // 0=Q 1=K 2=V
  const bf16* X = proj == 0 ? Xq : proj == 1 ? Xk : Xv;
  const float* bias = proj == 0 ? bq : proj == 1 ? bk : bv;

  const int tid = threadIdx.x;
  const int lane = tid & 63;
  const int wid = tid >> 6;
  const int g = lane >> 4;
  const int li = lane & 15;
  const int wr = (wid >> 1) * 64;
  const int wc = (wid & 1) * 64;

  f32x4 acc[4][4] = {};

  auto stage = [&](int bi, int k0) {
#pragma unroll
    for (int c = 0; c < 4; ++c) {
      int chunk = (c * 4 + wid) * 64 + lane;  // linear LDS 16B-slot index
      int r = chunk >> 3;
      int seg = (chunk & 7) ^ (r & 7);        // pre-swizzled global chunk
      gload_lds16(X + (size_t)(m0 + r) * D_MODELX + k0 + seg * 8,
                  &At[bi][((c * 4 + wid) * 64) * 8]);
      gload_lds16(W3 + (size_t)(n0 + r) * D_MODELX + k0 + seg * 8,
                  &Bt[bi][((c * 4 + wid) * 64) * 8]);
    }
  };

  stage(0, 0);
  stage(1, 64);

  const int NT = D_MODELX / 64;   // 16
  for (int t = 0; t < NT; ++t) {
    if (t < NT - 1)
      asm volatile("s_waitcnt vmcnt(8)" ::: "memory");   // own tile-t loads done
    else
      asm volatile("s_waitcnt vmcnt(0)" ::: "memory");
    __builtin_amdgcn_s_barrier();
    const int bi = t & 1;
    __builtin_amdgcn_s_setprio(1);
#pragma unroll
    for (int kk = 0; kk < 2; ++kk) {
      bf16x8 af[4], bfr[4];
#pragma unroll
      for (int m = 0; m < 4; ++m) {
        int row = wr + m * 16 + li;
        af[m] = *(const bf16x8*)&At[bi][row * 64 + (((kk * 4 + g) ^ (row & 7)) << 3)];
      }
#pragma unroll
      for (int n = 0; n < 4; ++n) {
        int row = wc + n * 16 + li;
        bfr[n] = *(const bf16x8*)&Bt[bi][row * 64 + (((kk * 4 + g) ^ (row & 7)) << 3)];
      }
#pragma unroll
      for (int m = 0; m < 4; ++m)
#pragma unroll
        for (int n = 0; n < 4; ++n)
          acc[m][n] = __builtin_amdgcn_mfma_f32_16x16x32_bf16(af[m], bfr[n],
                                                              acc[m][n], 0, 0, 0);
    }
    __builtin_amdgcn_s_setprio(0);
    __builtin_amdgcn_sched_barrier(0);   // pin MFMAs (+their lgkm waits) here
    __builtin_amdgcn_s_barrier();
    if (t + 2 < NT) stage(bi, (t + 2) * 64);
  }

  // epilogue. C/D layout: col = lane&15, row = (lane>>4)*4 + rg
#pragma unroll
  for (int m = 0; m < 4; ++m) {
#pragma unroll
    for (int n = 0; n < 4; ++n) {
      int col = n0 + wc + n * 16 + li;
      int col1k = col & 1023;
      int dh = col1k & 63;
      int h = col1k >> 6;
      if (proj == 2) {
        // V: write transposed (B,H,Dh,S); rg -> consecutive s -> 8B store
        int token0 = m0 + wr + m * 16 + g * 4;
        int s0 = token0 & (S_LEN - 1);
        int b0 = token0 >> 10;
        bf16x4 o;
#pragma unroll
        for (int rg = 0; rg < 4; ++rg) o[rg] = (bf16)(acc[m][n][rg] + bias[col1k]);
        *(bf16x4*)&vws[(((size_t)b0 * NHEAD + h) * DHEAD + dh) * S_LEN + s0] = o;
      } else {
#pragma unroll
        for (int rg = 0; rg < 4; ++rg) {
          int token = m0 + wr + m * 16 + g * 4 + rg;
          float v = acc[m][n][rg] + bias[col1k];
          float p = __shfl_xor(v, 1, 64);  // rope pair partner (adjacent col)
          int s = token & (S_LEN - 1);
          int b = token >> 10;
          int fi = dh >> 1;
          float cv = cosT[s * 32 + fi];
          float sv = sinT[s * 32 + fi];
          float vr = (dh & 1) ? (v * cv + p * sv) : (v * cv - p * sv);
          if (proj == 0) {
            vr += ubias[(h << 6) + dh];
            qws[(((size_t)b * NHEAD + h) * S_LEN + s) * DHEAD + dh] = (bf16)vr;
          } else {
            kws[(((size_t)b * NHEAD + h) * S_LEN + s) * DHEAD + dh] = (bf16)(vr * KSCALE);
          }
        }
      }
    }
  }
}

// ---------------------------------------------------------------- output GEMM
// out = ctx @ Wo^T + bo, fp32 out. Same counted-vmcnt dbuf pipeline.
__global__ __launch_bounds__(256) void gemm_out(
    const bf16* __restrict__ X, const bf16* __restrict__ W,
    const float* __restrict__ bias, float* __restrict__ outp) {
  __shared__ bf16 At[2][128 * 64];
  __shared__ bf16 Bt[2][128 * 64];
  const int id = blockIdx.x;
  const int swz = (id & 7) * 64 + (id >> 3);
  const int m0 = (swz >> 3) * 128;
  const int n0 = (swz & 7) * 128;
  const int tid = threadIdx.x;
  const int lane = tid & 63;
  const int wid = tid >> 6;
  const int g = lane >> 4;
  const int li = lane & 15;
  const int wr = (wid >> 1) * 64;
  const int wc = (wid & 1) * 64;

  f32x4 acc[4][4] = {};

  auto stage = [&](int bi, int k0) {
#pragma unroll
    for (int c = 0; c < 4; ++c) {
      int chunk = (c * 4 + wid) * 64 + lane;
      int r = chunk >> 3;
      int seg = (chunk & 7) ^ (r & 7);
      gload_lds16(X + (size_t)(m0 + r) * D_MODELX + k0 + seg * 8,
                  &At[bi][((c * 4 + wid) * 64) * 8]);
      gload_lds16(W + (size_t)(n0 + r) * D_MODELX + k0 + seg * 8,
                  &Bt[bi][((c * 4 + wid) * 64) * 8]);
    }
  };

  stage(0, 0);
  stage(1, 64);

  const int NT = D_MODELX / 64;   // 16
  for (int t = 0; t < NT; ++t) {
    if (t < NT - 1)
      asm volatile("s_waitcnt vmcnt(8)" ::: "memory");
    else
      asm volatile("s_waitcnt vmcnt(0)" ::: "memory");
    __builtin_amdgcn_s_barrier();
    const int bi = t & 1;
    __builtin_amdgcn_s_setprio(1);
#pragma unroll
    for (int kk = 0; kk < 2; ++kk) {
      bf16x8 af[4], bfr[4];
#pragma unroll
      for (int m = 0; m < 4; ++m) {
        int row = wr + m * 16 + li;
        af[m] = *(const bf16x8*)&At[bi][row * 64 + (((kk * 4 + g) ^ (row & 7)) << 3)];
      }
#pragma unroll
      for (int n = 0; n < 4; ++n) {
        int row = wc + n * 16 + li;
        bfr[n] = *(const bf16x8*)&Bt[bi][row * 64 + (((kk * 4 + g) ^ (row & 7)) << 3)];
      }
#pragma unroll
      for (int m = 0; m < 4; ++m)
#pragma unroll
        for (int n = 0; n < 4; ++n)
          acc[m][n] = __builtin_amdgcn_mfma_f32_16x16x32_bf16(af[m], bfr[n],
                                                              acc[m][n], 0, 0, 0);
    }
    __builtin_amdgcn_s_setprio(0);
    __builtin_amdgcn_sched_barrier(0);
    __builtin_amdgcn_s_barrier();
    if (t + 2 < NT) stage(bi, (t + 2) * 64);
  }

#pragma unroll
  for (int m = 0; m < 4; ++m)
#pragma unroll
    for (int n = 0; n < 4; ++n) {
      int col = n0 + wc + n * 16 + li;
#pragma unroll
      for (int rg = 0; rg < 4; ++rg) {
        int token = m0 + wr + m * 16 + g * 4 + rg;
        outp[(size_t)token * D_MODELX + col] = acc[m][n][rg] + bias[col];
      }
    }
}

// ---------------------------------------------------------------- attention
// Q: (B*H,S,64) bf16 (u_bias folded). K: pre-scaled by log2e/8. V: (B*H,64,S).
// mp: bit-packed mask. ctx: (B,S,1024) bf16. P=exp2(score), sums via ones-MFMA.
__global__ __launch_bounds__(256) void attn_fwd(
    const bf16* __restrict__ Q, const bf16* __restrict__ K,
    const bf16* __restrict__ V, const unsigned long long* __restrict__ mp,
    bf16* __restrict__ ctx) {
  __shared__ bf16 Kl[2][64 * 64];     // [t][d], XOR-swizzled
  __shared__ bf16 Vt[2][64 * 64];     // [d][t], XOR-swizzled
  __shared__ bf16 Pl[4][16 * 64];     // per-wave P [q][t], XOR-swizzled

  const int id = blockIdx.x;          // 2048 = 8 XCD * 256
  const int swz = (id & 7) * 256 + (id >> 3);
  const int bh = swz >> 4;
  const int qblk = swz & 15;
  const int tid = threadIdx.x;
  const int lane = tid & 63;
  const int wid = tid >> 6;
  const int b = bh >> 4;
  const int h = bh & 15;
  const int g = lane >> 4;
  const int li = lane & 15;
  const int q0 = qblk * 64 + wid * 16;

  const bf16* qbase = Q + ((size_t)bh * S_LEN + q0) * DHEAD;
  bf16x8 qf[2];
  qf[0] = *(const bf16x8*)&qbase[(size_t)li * DHEAD + g * 8];
  qf[1] = *(const bf16x8*)&qbase[(size_t)li * DHEAD + 32 + g * 8];

  bf16x8 onesf;
#pragma unroll
  for (int j = 0; j < 8; ++j) onesf[j] = (bf16)1.0f;

  f32x4 ctxacc[4] = {};
  f32x4 sacc = {};

  const bf16* gk = K + (size_t)bh * S_LEN * DHEAD;       // [t][d]
  const bf16* gv = V + (size_t)bh * DHEAD * S_LEN;       // [d][t]
  const unsigned long long* mrowp = mp + ((size_t)b * S_LEN + q0) * 16;

  const int srow = lane >> 3;                // 0..7 within 8-row group
  const int schunk = (lane & 7) ^ srow;      // pre-swizzled global chunk

  auto stage = [&](int bi, int it) {
    int t0 = it * 64;
#pragma unroll
    for (int j = 0; j < 2; ++j) {
      int row = wid * 16 + j * 8 + srow;
      gload_lds16(gk + ((size_t)(t0 + row)) * DHEAD + schunk * 8,
                  &Kl[bi][(wid * 16 + j * 8) * 64]);
      gload_lds16(gv + (size_t)row * S_LEN + t0 + schunk * 8,
                  &Vt[bi][(wid * 16 + j * 8) * 64]);
    }
  };

  stage(0, 0);
  int buf = 0;

  for (int it = 0; it < S_LEN / 64; ++it) {
    asm volatile("s_waitcnt vmcnt(0)" ::: "memory");
    __builtin_amdgcn_s_barrier();
    if (it + 1 < S_LEN / 64) stage(buf ^ 1, it + 1);

    // packed mask words for this tile (one 64-bit word per q-row)
    unsigned long long mw[4];
#pragma unroll
    for (int rg = 0; rg < 4; ++rg)
      mw[rg] = mrowp[(size_t)(g * 4 + rg) * 16 + it];

    // QK^T: sc[tt][rg] = log2-domain score[q = g*4+rg][t-local = tt*16 + li]
    f32x4 sc[4];
    __builtin_amdgcn_s_setprio(1);
#pragma unroll
    for (int tt = 0; tt < 4; ++tt) {
      int row = tt * 16 + li;
      int sz = li & 7;
      bf16x8 kf0 = *(const bf16x8*)&Kl[buf][row * 64 + ((g ^ sz) << 3)];
      bf16x8 kf1 = *(const bf16x8*)&Kl[buf][row * 64 + (((g + 4) ^ sz) << 3)];
      f32x4 a = {};
      a = __builtin_amdgcn_mfma_f32_16x16x32_bf16(qf[0], kf0, a, 0, 0, 0);
      a = __builtin_amdgcn_mfma_f32_16x16x32_bf16(qf[1], kf1, a, 0, 0, 0);
      sc[tt] = a;
    }
    __builtin_amdgcn_s_setprio(0);

    // P = exp2(score), masked -> 0; write to per-wave LDS (swizzled)
#pragma unroll
    for (int rg = 0; rg < 4; ++rg) {
      unsigned long long msh = mw[rg] >> li;
      unsigned int mlo = (unsigned int)msh;
      unsigned int mhi = (unsigned int)(msh >> 32);
      int qq = g * 4 + rg;
#pragma unroll
      for (int tt = 0; tt < 4; ++tt) {
        unsigned int half = (tt & 2) ? mhi : mlo;
        unsigned int bit = (half >> ((tt & 1) << 4)) & 1u;
        float p = exp2f(sc[tt][rg]);
        p = bit ? 0.0f : p;
        int t = tt * 16 + li;
        Pl[wid][qq * 64 + (t ^ ((qq & 7) << 3))] = (bf16)p;
      }
    }

    // PV + row-sum: ctx[q][d] += P[q][t]*Vt[d][t];  sacc[q] += P[q][t]*1
    __builtin_amdgcn_s_setprio(1);
#pragma unroll
    for (int sub = 0; sub < 2; ++sub) {
      bf16x8 pf = *(const bf16x8*)&Pl[wid][li * 64 + (((sub * 4 + g) ^ (li & 7)) << 3)];
      sacc = __builtin_amdgcn_mfma_f32_16x16x32_bf16(pf, onesf, sacc, 0, 0, 0);
#pragma unroll
      for (int dd = 0; dd < 4; ++dd) {
        int row = dd * 16 + li;
        bf16x8 vf = *(const bf16x8*)&Vt[buf][row * 64 + (((sub * 4 + g) ^ (row & 7)) << 3)];
        ctxacc[dd] = __builtin_amdgcn_mfma_f32_16x16x32_bf16(pf, vf, ctxacc[dd], 0, 0, 0);
      }
    }
    __builtin_amdgcn_s_setprio(0);
    buf ^= 1;
  }

  // normalize + store ctx (B,S,D) bf16
  float inv[4];
#pragma unroll
  for (int rg = 0; rg < 4; ++rg) inv[rg] = 1.0f / sacc[rg];
#pragma unroll
  for (int dd = 0; dd < 4; ++dd)
#pragma unroll
    for (int rg = 0; rg < 4; ++rg) {
      float vout = ctxacc[dd][rg] * inv[rg];
      int s = q0 + g * 4 + rg;
      int d = h * 64 + dd * 16 + li;
      ctx[((size_t)b * S_LEN + s) * D_MODELX + d] = (bf16)vout;
    }
}

// ---------------------------------------------------------------- launcher
extern "C" void kernel_launch(void* const* d_in, const int* in_sizes, int n_in,
                              void* d_out, int out_size, void* d_ws, size_t ws_size,
                              hipStream_t stream) {
  const float* query = (const float*)d_in[0];
  const float* key   = (const float*)d_in[1];
  const float* value = (const float*)d_in[2];
  const int*   mask  = (const int*)d_in[3];
  const float* Wq = (const float*)d_in[4];
  const float* bq = (const float*)d_in[5];
  const float* Wk = (const float*)d_in[6];
  const float* bk = (const float*)d_in[7];
  const float* Wv = (const float*)d_in[8];
  const float* bv = (const float*)d_in[9];
  const float* ub = (const float*)d_in[10];
  const float* Wo = (const float*)d_in[11];
  const float* bo = (const float*)d_in[12];
  float* out = (float*)d_out;

  char* wsb = (char*)d_ws;
  size_t off = 0;
  auto give = [&](size_t bytes) -> char* {
    char* p = wsb + off;
    off += (bytes + 255) & ~(size_t)255;
    return p;
  };
  const size_t ACT = (size_t)NTOK * D_MODELX * 2;   // 16.78 MB
  const size_t WB  = (size_t)D_MODELX * D_MODELX * 2;
  bf16* Xq   = (bf16*)give(ACT);
  bf16* Xk   = (bf16*)give(ACT);
  bf16* Xv   = (bf16*)give(ACT);
  bf16* Wqb  = (bf16*)give(WB);    // Wqb/Wkb/Wvb contiguous -> W3 [3072][1024]
  bf16* Wkb  = (bf16*)give(WB);
  bf16* Wvb  = (bf16*)give(WB);
  bf16* Wob  = (bf16*)give(WB);
  bf16* qws  = (bf16*)give(ACT);   // (B,H,S,Dh)
  bf16* kws  = (bf16*)give(ACT);   // (B,H,S,Dh), pre-scaled
  bf16* vws  = (bf16*)give(ACT);   // (B,H,Dh,S)  TRANSPOSED
  unsigned long long* mp = (unsigned long long*)give((size_t)BATCH * S_LEN * 16 * 8);
  float* cosT = (float*)give((size_t)S_LEN * 32 * 4);
  float* sinT = (float*)give((size_t)S_LEN * 32 * 4);
  bf16* ctxw = Xq;                 // Xq dead after QKV GEMM; reuse (B,S,D)

  preproc<<<PRE_TOTAL, 256, 0, stream>>>(query, key, value, Wq, Wk, Wv, Wo, mask,
                                         Xq, Xk, Xv, Wqb, Wkb, Wvb, Wob, mp,
                                         cosT, sinT);

  gemm_qkv<<<1536, 256, 0, stream>>>(Xq, Xk, Xv, Wqb, bq, bk, bv,
                                     qws, kws, vws, cosT, sinT, ub);

  attn_fwd<<<2048, 256, 0, stream>>>(qws, kws, vws, mp, ctxw);

  gemm_out<<<512, 256, 0, stream>>>(ctxw, Wob, bo, out);
}